// Round 1
// baseline (1663.645 us; speedup 1.0000x reference)
//
#include <hip/hip_runtime.h>
#include <math.h>

// Problem constants (from reference)
#define BB 2
#define LL 1024
#define HIDD 1024
#define NH 4
#define DD 256          // DK == DV == 256
#define NCH 32          // number of chunks (L / 32)
#define ROWS 2048       // B*L
#define HROWS 8192      // B*L*NH

typedef long long i64;

__device__ __forceinline__ float sigmoidf_(float x) { return 1.0f / (1.0f + expf(-x)); }

// ---------------- block reduction helper (blockDim == 256) ----------------
template<int N>
__device__ __forceinline__ void block_reduce_sum(float* v, float* scratch) {
  int lane = threadIdx.x & 63, wid = threadIdx.x >> 6;
#pragma unroll
  for (int i = 0; i < N; i++) {
    float x = v[i];
#pragma unroll
    for (int off = 1; off < 64; off <<= 1) x += __shfl_xor(x, off);
    if (lane == 0) scratch[wid * N + i] = x;
  }
  __syncthreads();
#pragma unroll
  for (int i = 0; i < N; i++)
    v[i] = scratch[i] + scratch[N + i] + scratch[2 * N + i] + scratch[3 * N + i];
  __syncthreads();
}

// ---------------- generic 128x128 fp32 GEMM, C = A @ B ----------------
// A columns may be gathered from 4 part-buffers (split by a_shift), same for B.
__global__ __launch_bounds__(256) void gemm128_kernel(
    const float* __restrict__ A0, const float* __restrict__ A1,
    const float* __restrict__ A2, const float* __restrict__ A3,
    int a_shift, int a_mask, int lda,
    const float* __restrict__ B0, const float* __restrict__ B1,
    const float* __restrict__ B2, const float* __restrict__ B3,
    int b_shift, int b_mask, int ldb,
    float* __restrict__ C, int ldc, int K) {
  __shared__ float As[16][128];
  __shared__ float Bs[16][128];
  int t = threadIdx.x;
  int tx = t & 15, ty = t >> 4;
  int n0 = blockIdx.x * 128, m0 = blockIdx.y * 128;
  const float* Ap[4] = {A0, A1, A2, A3};
  const float* Bp[4] = {B0, B1, B2, B3};
  float acc[8][8];
#pragma unroll
  for (int i = 0; i < 8; i++)
#pragma unroll
    for (int j = 0; j < 8; j++) acc[i][j] = 0.0f;

  for (int k0 = 0; k0 < K; k0 += 16) {
#pragma unroll
    for (int i = 0; i < 2; i++) {
      int fid = t + i * 256;
      int row = fid >> 2, kq = (fid & 3) * 4;
      int col = k0 + kq;
      const float* ap = Ap[(col >> a_shift) & 3];
      float4 av = *(const float4*)(ap + (i64)(m0 + row) * lda + (col & a_mask));
      As[kq + 0][row] = av.x; As[kq + 1][row] = av.y;
      As[kq + 2][row] = av.z; As[kq + 3][row] = av.w;
    }
#pragma unroll
    for (int i = 0; i < 2; i++) {
      int fid = t + i * 256;
      int r = fid >> 5, cq = (fid & 31) * 4;
      int col = n0 + cq;
      const float* bp = Bp[(col >> b_shift) & 3];
      *(float4*)&Bs[r][cq] = *(const float4*)(bp + (i64)(k0 + r) * ldb + (col & b_mask));
    }
    __syncthreads();
#pragma unroll
    for (int kk = 0; kk < 16; kk++) {
      float a[8], b[8];
      *(float4*)&a[0] = *(const float4*)&As[kk][ty * 8];
      *(float4*)&a[4] = *(const float4*)&As[kk][ty * 8 + 4];
      *(float4*)&b[0] = *(const float4*)&Bs[kk][tx * 8];
      *(float4*)&b[4] = *(const float4*)&Bs[kk][tx * 8 + 4];
#pragma unroll
      for (int ii = 0; ii < 8; ii++)
#pragma unroll
        for (int jj = 0; jj < 8; jj++) acc[ii][jj] += a[ii] * b[jj];
    }
    __syncthreads();
  }
#pragma unroll
  for (int ii = 0; ii < 8; ii++) {
    float4 v0 = make_float4(acc[ii][0], acc[ii][1], acc[ii][2], acc[ii][3]);
    float4 v1 = make_float4(acc[ii][4], acc[ii][5], acc[ii][6], acc[ii][7]);
    float* cp = C + (i64)(m0 + ty * 8 + ii) * ldc + n0 + tx * 8;
    *(float4*)cp = v0;
    *(float4*)(cp + 4) = v1;
  }
}

// ---------------- causal depthwise conv (K=4) + silu ----------------
__global__ __launch_bounds__(256) void conv_silu_kernel(
    const float* __restrict__ pre, int ldpre, int coff,
    const float* __restrict__ w, float* __restrict__ out) {
  int idx = blockIdx.x * 256 + threadIdx.x;     // over ROWS*1024
  int c = idx & (HIDD - 1);
  int row = idx >> 10;
  int l = row & (LL - 1);
  float4 wv = *(const float4*)(w + c * 4);      // w[c][0..3]
  const float* base = pre + (i64)row * ldpre + coff + c;
  float acc = wv.w * base[0];                   // tap j=3 -> x[t]
  if (l >= 1) acc += wv.z * base[-ldpre];
  if (l >= 2) acc += wv.y * base[-2 * ldpre];
  if (l >= 3) acc += wv.x * base[-3 * ldpre];
  out[(i64)row * HIDD + c] = acc * sigmoidf_(acc);
}

// ---------------- beta = sigmoid(x @ Wb), Wb [1024,4] ----------------
__global__ __launch_bounds__(256) void beta_kernel(
    const float* __restrict__ x, const float* __restrict__ Wb, float* __restrict__ beta) {
  int row = blockIdx.x, t = threadIdx.x;
  __shared__ float sc[16];
  float a[4] = {0, 0, 0, 0};
  for (int c = t; c < 1024; c += 256) {
    float xv = x[(i64)row * 1024 + c];
    float4 wv = *(const float4*)(Wb + c * 4);
    a[0] += xv * wv.x; a[1] += xv * wv.y; a[2] += xv * wv.z; a[3] += xv * wv.w;
  }
  block_reduce_sum<4>(a, sc);
  if (t == 0) {
#pragma unroll
    for (int g = 0; g < 4; g++) beta[row * 4 + g] = sigmoidf_(a[g]);
  }
}

// ---------------- l2norm(q,k), v*beta, kn*beta ----------------
__global__ __launch_bounds__(256) void preprocess_kernel(
    const float* __restrict__ q, const float* __restrict__ k, const float* __restrict__ v,
    const float* __restrict__ beta, float* __restrict__ qn, float* __restrict__ kn,
    float* __restrict__ vb, float* __restrict__ kb) {
  int row = blockIdx.x, t = threadIdx.x;     // row over HROWS, t = d
  __shared__ float sc[8];
  i64 base = (i64)row * 256 + t;
  float qv = q[base], kv = k[base], vv = v[base];
  float vals[2] = {qv * qv, kv * kv};
  block_reduce_sum<2>(vals, sc);
  float qi = rsqrtf(vals[0] + 1e-6f), ki = rsqrtf(vals[1] + 1e-6f);
  float bet = beta[row];
  float knv = kv * ki;
  qn[base] = qv * qi;
  kn[base] = knv;
  vb[base] = vv * bet;
  kb[base] = knv * bet;
}

// ---------------- phase A: per-chunk M, attn, and UT-transform (u, w) ----------------
__global__ __launch_bounds__(256) void phaseA_kernel(
    const float* __restrict__ qn, const float* __restrict__ kn,
    const float* __restrict__ vb, const float* __restrict__ kb,
    float* __restrict__ u_g, float* __restrict__ w_g, float* __restrict__ attn_g) {
  __shared__ float KN[32][260];
  __shared__ float Ms[32][32];
  int blk = blockIdx.x, t = threadIdx.x;
  int i = blk & 31, bh = blk >> 5;
  int rbase = ((bh >> 2) * LL + i * 32) * NH + (bh & 3);   // row index of chunk pos c: rbase + c*NH
  int bhn = bh * NCH + i;
  // stage kn chunk [32][256]
#pragma unroll
  for (int ii = 0; ii < 8; ii++) {
    int fid = t + ii * 256;
    int c = fid >> 6, dq = (fid & 63) << 2;
    *(float4*)&KN[c][dq] = *(const float4*)(kn + (i64)(rbase + c * NH) * 256 + dq);
  }
  __syncthreads();
  // M[c][e] = kb_c . kn_e ; attn[c][e] = qn_c . kn_e
  int c = t >> 3, e0 = (t & 7) * 4;
  const float* kbp = kb + (i64)(rbase + c * NH) * 256;
  const float* qp = qn + (i64)(rbase + c * NH) * 256;
  float am[4] = {0, 0, 0, 0}, aa[4] = {0, 0, 0, 0};
  for (int d = 0; d < 256; d += 4) {
    float4 kv = *(const float4*)(kbp + d);
    float4 qv = *(const float4*)(qp + d);
#pragma unroll
    for (int z = 0; z < 4; z++) {
      float4 nv = *(const float4*)&KN[e0 + z][d];
      am[z] += kv.x * nv.x + kv.y * nv.y + kv.z * nv.z + kv.w * nv.w;
      aa[z] += qv.x * nv.x + qv.y * nv.y + qv.z * nv.z + qv.w * nv.w;
    }
  }
#pragma unroll
  for (int z = 0; z < 4; z++) {
    int e = e0 + z;
    Ms[c][e] = (e < c) ? am[z] : 0.0f;
    attn_g[(i64)bhn * 1024 + c * 32 + e] = (e <= c) ? aa[z] : 0.0f;
  }
  __syncthreads();
  // forward substitution, thread = column d: (I + tril(M,-1)) u = vb ; same for w with rhs kb
  float uc[32], wc[32];
#pragma unroll
  for (int cc = 0; cc < 32; cc++) {
    float uval = vb[(i64)(rbase + cc * NH) * 256 + t];
    float wval = kb[(i64)(rbase + cc * NH) * 256 + t];
#pragma unroll
    for (int c2 = 0; c2 < cc; c2++) {
      float m = Ms[cc][c2];
      uval -= m * uc[c2];
      wval -= m * wc[c2];
    }
    uc[cc] = uval; wc[cc] = wval;
    u_g[((i64)bhn * 32 + cc) * 256 + t] = uval;
    w_g[((i64)bhn * 32 + cc) * 256 + t] = wval;
  }
}

// ---------------- phase B: sequential chunk scan, dv split into 16-col blocks ----------------
__global__ __launch_bounds__(256) void phaseB_kernel(
    const float* __restrict__ qn, const float* __restrict__ kn,
    const float* __restrict__ u_g, const float* __restrict__ w_g,
    const float* __restrict__ attn_g, float* __restrict__ dlt) {
  __shared__ float S[16][260];   // S^T block: [j][d], padded
  __shared__ float Up[32][16];   // u' chunk slice
  __shared__ float At[32][32];   // attn
  int t = threadIdx.x;
  int bh = blockIdx.x >> 4, jb = blockIdx.x & 15;
  int j0 = jb * 16;
  int j = t & 15, cg = t >> 4;   // cg in 0..15
  int b_ = bh >> 2, h_ = bh & 3;
  for (int idx = t; idx < 16 * 260; idx += 256) ((float*)S)[idx] = 0.0f;
  __syncthreads();

  for (int i = 0; i < NCH; i++) {
    int rbase = (b_ * LL + i * 32) * NH + h_;
    i64 ubase = ((i64)(bh * NCH + i)) * 32 * 256;
    // stage attn_i
#pragma unroll
    for (int z = 0; z < 4; z++)
      ((float*)At)[t + z * 256] = attn_g[(i64)(bh * NCH + i) * 1024 + t + z * 256];
    // u'[c][j] = u[c][j] - sum_d w[c][d] * S[d][j], c = cg and cg+16
    const float* w0p = w_g + ubase + (i64)cg * 256;
    const float* w1p = w0p + 16 * 256;
    float ua0 = 0.0f, ua1 = 0.0f;
    for (int d = 0; d < 256; d += 4) {
      float4 s4 = *(const float4*)&S[j][d];
      float4 a4 = *(const float4*)(w0p + d);
      float4 b4 = *(const float4*)(w1p + d);
      ua0 += a4.x * s4.x + a4.y * s4.y + a4.z * s4.z + a4.w * s4.w;
      ua1 += b4.x * s4.x + b4.y * s4.y + b4.z * s4.z + b4.w * s4.w;
    }
    float up0 = u_g[ubase + (i64)cg * 256 + j0 + j] - ua0;
    float up1 = u_g[ubase + (i64)(cg + 16) * 256 + j0 + j] - ua1;
    Up[cg][j] = up0;
    Up[cg + 16][j] = up1;
    __syncthreads();
    // o = q @ S + tril(attn) @ u'
    const float* q0p = qn + (i64)(rbase + cg * NH) * 256;
    const float* q1p = qn + (i64)(rbase + (cg + 16) * NH) * 256;
    float oa0 = 0.0f, oa1 = 0.0f;
    for (int d = 0; d < 256; d += 4) {
      float4 s4 = *(const float4*)&S[j][d];
      float4 a4 = *(const float4*)(q0p + d);
      float4 b4 = *(const float4*)(q1p + d);
      oa0 += a4.x * s4.x + a4.y * s4.y + a4.z * s4.z + a4.w * s4.w;
      oa1 += b4.x * s4.x + b4.y * s4.y + b4.z * s4.z + b4.w * s4.w;
    }
    for (int c2 = 0; c2 <= cg; c2++)      oa0 += At[cg][c2] * Up[c2][j];
    for (int c2 = 0; c2 <= cg + 16; c2++) oa1 += At[cg + 16][c2] * Up[c2][j];
    dlt[(i64)(rbase + cg * NH) * 256 + j0 + j] = oa0;
    dlt[(i64)(rbase + (cg + 16) * NH) * 256 + j0 + j] = oa1;
    __syncthreads();
    // S[d][j] += sum_c kn[c][d] * u'[c][j]; thread owns (j, d0=cg*16..+15)
    int d0 = cg * 16;
    float upc[32];
#pragma unroll
    for (int c2 = 0; c2 < 32; c2++) upc[c2] = Up[c2][j];
    float acc[16];
#pragma unroll
    for (int z = 0; z < 16; z++) acc[z] = 0.0f;
    for (int c2 = 0; c2 < 32; c2++) {
      const float* kp = kn + (i64)(rbase + c2 * NH) * 256 + d0;
      float4 k0 = *(const float4*)(kp);
      float4 k1 = *(const float4*)(kp + 4);
      float4 k2 = *(const float4*)(kp + 8);
      float4 k3 = *(const float4*)(kp + 12);
      float uu = upc[c2];
      acc[0] += k0.x * uu; acc[1] += k0.y * uu; acc[2] += k0.z * uu; acc[3] += k0.w * uu;
      acc[4] += k1.x * uu; acc[5] += k1.y * uu; acc[6] += k1.z * uu; acc[7] += k1.w * uu;
      acc[8] += k2.x * uu; acc[9] += k2.y * uu; acc[10] += k2.z * uu; acc[11] += k2.w * uu;
      acc[12] += k3.x * uu; acc[13] += k3.y * uu; acc[14] += k3.z * uu; acc[15] += k3.w * uu;
    }
#pragma unroll
    for (int z = 0; z < 16; z++) S[j][d0 + z] += acc[z];
    __syncthreads();
  }
}

// ---------------- per-head depthwise causal FIR ----------------
__global__ __launch_bounds__(256) void fir_kernel(
    const float* __restrict__ v, const float* __restrict__ f, float* __restrict__ out, int K) {
  __shared__ float fb[256 * 31];
  int row = blockIdx.x, t = threadIdx.x;   // row over HROWS, t = d
  int h = row & 3, l = (row >> 2) & (LL - 1);
  for (int idx = t; idx < 256 * K; idx += 256) fb[idx] = f[h * 256 * K + idx];
  __syncthreads();
  float acc = 0.0f;
  int jmin = (K - 1) - l; if (jmin < 0) jmin = 0;
  for (int jj = jmin; jj < K; jj++) {
    int dl = jj - (K - 1);
    acc += fb[t * K + jj] * v[(i64)(row + dl * NH) * 256 + t];
  }
  out[(i64)row * 256 + t] = acc;
}

// ---------------- per-(row,branch) stats: mean, rms, max ----------------
__global__ __launch_bounds__(256) void stats_kernel(
    const float* __restrict__ fs, const float* __restrict__ fl,
    const float* __restrict__ dlt, const float* __restrict__ v, float* __restrict__ stat) {
  int row = blockIdx.x, t = threadIdx.x;
  __shared__ float sc[8];
  __shared__ float scm[4];
  const float* brs[4] = {fs, fl, dlt, v};
#pragma unroll
  for (int p = 0; p < 4; p++) {
    float x = brs[p][(i64)row * 256 + t];
    float vals[2] = {x, x * x};
    block_reduce_sum<2>(vals, sc);
    float m = x;
#pragma unroll
    for (int off = 1; off < 64; off <<= 1) m = fmaxf(m, __shfl_xor(m, off));
    int lane = t & 63, wid = t >> 6;
    if (lane == 0) scm[wid] = m;
    __syncthreads();
    if (t == 0) {
      float mx = fmaxf(fmaxf(scm[0], scm[1]), fmaxf(scm[2], scm[3]));
      stat[row * 12 + p * 3 + 0] = vals[0] * (1.0f / 256.0f);
      stat[row * 12 + p * 3 + 1] = sqrtf(fmaxf(vals[1] * (1.0f / 256.0f), 1e-8f));
      stat[row * 12 + p * 3 + 2] = mx;
    }
    __syncthreads();
  }
}

// ---------------- W1 stat-block column sums (12 blocks of 256 rows) ----------------
__global__ __launch_bounds__(256) void wsum_kernel(const float* __restrict__ W1, float* __restrict__ Wsum) {
  int s = blockIdx.x, t = threadIdx.x;
  for (int o = t; o < 512; o += 256) {
    float acc = 0.0f;
    const float* p = W1 + (i64)(1024 + s * 256) * 512 + o;
    for (int r = 0; r < 256; r++) acc += p[r * 512];
    Wsum[s * 512 + o] = acc;
  }
}

// ---------------- gate MLP tail: gelu(hmid) @ W2, softmax w/ temp + floor ----------------
__global__ __launch_bounds__(256) void gate_kernel(
    const float* __restrict__ hbase, const float* __restrict__ brW,
    const float* __restrict__ stat, const float* __restrict__ wsum,
    const float* __restrict__ gb1, const float* __restrict__ gW2,
    const float* __restrict__ gb2, const float* __restrict__ temp,
    const float* __restrict__ epsf, float* __restrict__ gw) {
  int row = blockIdx.x, t = threadIdx.x;
  int bl = row >> 2, h = row & 3;
  __shared__ float sc[16];
  float st[12];
#pragma unroll
  for (int s = 0; s < 12; s++) st[s] = stat[row * 12 + s];
  float lg[4] = {0, 0, 0, 0};
  for (int o = t; o < 512; o += 256) {
    float hm = hbase[(i64)bl * 512 + o] + brW[(i64)row * 512 + o] + gb1[o];
#pragma unroll
    for (int s = 0; s < 12; s++) hm += st[s] * wsum[s * 512 + o];
    float ge = 0.5f * hm * (1.0f + erff(hm * 0.70710678118654752f));
    float4 w2 = *(const float4*)(gW2 + o * 4);
    lg[0] += ge * w2.x; lg[1] += ge * w2.y; lg[2] += ge * w2.z; lg[3] += ge * w2.w;
  }
  block_reduce_sum<4>(lg, sc);
  if (t == 0) {
    float tt = fminf(fmaxf(temp[h], 0.2f), 10.0f);
    float l0 = (lg[0] + gb2[0]) / tt;
    float l1 = (lg[1] + gb2[1]) / tt;
    float l2 = (lg[2] + gb2[2]) / tt;
    float l3 = (lg[3] + gb2[3]) / tt;
    float m = fmaxf(fmaxf(l0, l1), fmaxf(l2, l3));
    float e0 = expf(l0 - m), e1 = expf(l1 - m), e2 = expf(l2 - m), e3 = expf(l3 - m);
    float ssum = e0 + e1 + e2 + e3;
    float w0 = e0 / ssum, w1 = e1 / ssum, w2 = e2 / ssum, w3 = e3 / ssum;
    w0 = fmaxf(w0, fminf(fmaxf(epsf[h * 4 + 0], 1e-7f), 0.1f));
    w1 = fmaxf(w1, fminf(fmaxf(epsf[h * 4 + 1], 1e-7f), 0.1f));
    w2 = fmaxf(w2, fminf(fmaxf(epsf[h * 4 + 2], 1e-7f), 0.1f));
    w3 = fmaxf(w3, fminf(fmaxf(epsf[h * 4 + 3], 1e-7f), 0.1f));
    float s2 = w0 + w1 + w2 + w3;
    gw[row * 4 + 0] = w0 / s2;
    gw[row * 4 + 1] = w1 / s2;
    gw[row * 4 + 2] = w2 / s2;
    gw[row * 4 + 3] = w3 / s2;
  }
}

// ---------------- weighted mix + RMS norm ----------------
__global__ __launch_bounds__(256) void mix_kernel(
    const float* __restrict__ fs, const float* __restrict__ fl,
    const float* __restrict__ dlt, const float* __restrict__ v,
    const float* __restrict__ gw, const float* __restrict__ onw, float* __restrict__ out) {
  int row = blockIdx.x, t = threadIdx.x;
  __shared__ float sc[4];
  i64 base = (i64)row * 256 + t;
  float4 wv = *(const float4*)(gw + row * 4);
  float o = wv.x * fs[base] + wv.y * fl[base] + wv.z * dlt[base] + wv.w * v[base];
  float vals[1] = {o * o};
  block_reduce_sum<1>(vals, sc);
  float scale = rsqrtf(vals[0] * (1.0f / 256.0f) + 1e-5f);
  out[base] = o * scale * onw[t];
}

extern "C" void kernel_launch(void* const* d_in, const int* in_sizes, int n_in,
                              void* d_out, int out_size, void* d_ws, size_t ws_size,
                              hipStream_t stream) {
  (void)in_sizes; (void)n_in; (void)out_size; (void)ws_size;
  const float* x    = (const float*)d_in[0];
  const float* Wq   = (const float*)d_in[1];
  const float* Wk   = (const float*)d_in[2];
  const float* Wv   = (const float*)d_in[3];
  const float* Wb   = (const float*)d_in[4];
  const float* qcw  = (const float*)d_in[5];
  const float* kcw  = (const float*)d_in[6];
  const float* vcw  = (const float*)d_in[7];
  const float* gW1  = (const float*)d_in[8];
  const float* gb1  = (const float*)d_in[9];
  const float* gW2  = (const float*)d_in[10];
  const float* gb2  = (const float*)d_in[11];
  const float* temp = (const float*)d_in[12];
  const float* epsf = (const float*)d_in[13];
  const float* onw  = (const float*)d_in[14];
  const float* Wo   = (const float*)d_in[15];
  const float* firs = (const float*)d_in[16];
  const float* firl = (const float*)d_in[17];
  float* out = (float*)d_out;

  float* ws = (float*)d_ws;
  // workspace layout (floats); regions reused once their producer is dead
  float* qkv_pre = ws + 0;           // 2048*3072  (dead after conv)
  float* u_g     = ws + 0;           // 8*32*32*256
  float* w_g     = ws + 2097152;
  float* attn_g  = ws + 4194304;     // 8*32*1024
  float* qbuf    = ws + 6291456;     // 8192*256   (dead after preprocess)
  float* kbuf    = ws + 8388608;
  float* branchW = qbuf;             // 8192*512 over q+k region
  float* vbuf    = ws + 10485760;    // lives: branch input
  float* betab   = ws + 12582912;    // 8192
  float* qn      = ws + 12591104;
  float* kn      = ws + 14688256;
  float* vb      = ws + 16785408;    // dead after phaseA
  float* omix    = vb;               // 2048*1024
  float* kb      = ws + 18882560;    // dead after phaseA
  float* hbase   = kb;               // 2048*512
  float* dlt     = ws + 20979712;
  float* fs      = ws + 23076864;
  float* fl      = ws + 25174016;
  float* stat    = ws + 27271168;    // 8192*12
  float* wsum    = ws + 27369472;    // 12*512
  float* gw      = ws + 27375616;    // 8192*4

  // 1) qkv = x @ [Wq|Wk|Wv]
  gemm128_kernel<<<dim3(24, 16), 256, 0, stream>>>(
      x, x, x, x, 20, 0x7FFFFFFF, 1024,
      Wq, Wk, Wv, Wv, 10, 1023, 1024,
      qkv_pre, 3072, 1024);
  // 2) conv + silu
  conv_silu_kernel<<<8192, 256, 0, stream>>>(qkv_pre, 3072, 0, qcw, qbuf);
  conv_silu_kernel<<<8192, 256, 0, stream>>>(qkv_pre, 3072, 1024, kcw, kbuf);
  conv_silu_kernel<<<8192, 256, 0, stream>>>(qkv_pre, 3072, 2048, vcw, vbuf);
  // 3) beta
  beta_kernel<<<2048, 256, 0, stream>>>(x, Wb, betab);
  // 4) l2norm + scale
  preprocess_kernel<<<8192, 256, 0, stream>>>(qbuf, kbuf, vbuf, betab, qn, kn, vb, kb);
  // 5) phase A: u, w, attn per chunk
  phaseA_kernel<<<256, 256, 0, stream>>>(qn, kn, vb, kb, u_g, w_g, attn_g);
  // 6) phase B: chunk scan -> delta_o
  phaseB_kernel<<<128, 256, 0, stream>>>(qn, kn, u_g, w_g, attn_g, dlt);
  // 7) FIR branches
  fir_kernel<<<8192, 256, 0, stream>>>(vbuf, firs, fs, 3);
  fir_kernel<<<8192, 256, 0, stream>>>(vbuf, firl, fl, 31);
  // 8) branch stats
  stats_kernel<<<8192, 256, 0, stream>>>(fs, fl, dlt, vbuf, stat);
  // 9) W1 stat-block column sums
  wsum_kernel<<<12, 256, 0, stream>>>(gW1, wsum);
  // 10) hidden part of gate: x @ W1[0:1024]
  gemm128_kernel<<<dim3(4, 16), 256, 0, stream>>>(
      x, x, x, x, 20, 0x7FFFFFFF, 1024,
      gW1, gW1, gW1, gW1, 20, 0x7FFFFFFF, 512,
      hbase, 512, 1024);
  // 11) branch part of gate: [fs|fl|dlt|v] @ W1[4096:5120]
  gemm128_kernel<<<dim3(4, 64), 256, 0, stream>>>(
      fs, fl, dlt, vbuf, 8, 255, 256,
      gW1 + (i64)4096 * 512, gW1 + (i64)4096 * 512, gW1 + (i64)4096 * 512, gW1 + (i64)4096 * 512,
      20, 0x7FFFFFFF, 512,
      branchW, 512, 1024);
  // 12) gate tail
  gate_kernel<<<8192, 256, 0, stream>>>(hbase, branchW, stat, wsum, gb1, gW2, gb2, temp, epsf, gw);
  // 13) mix + RMS norm
  mix_kernel<<<8192, 256, 0, stream>>>(fs, fl, dlt, vbuf, gw, onw, omix);
  // 14) final projection
  gemm128_kernel<<<dim3(8, 16), 256, 0, stream>>>(
      omix, omix, omix, omix, 20, 0x7FFFFFFF, 1024,
      Wo, Wo, Wo, Wo, 20, 0x7FFFFFFF, 1024,
      out, 1024, 1024);
}

// Round 3
// 553.094 us; speedup vs baseline: 3.0079x; 3.0079x over previous
//
#include <hip/hip_runtime.h>
#include <math.h>

// Problem constants
#define BB 2
#define LL 1024
#define HIDD 1024
#define NH 4
#define DD 256
#define NCH 32
#define ROWS 2048
#define HROWS 8192

typedef long long i64;
typedef unsigned short u16t;
typedef unsigned int u32t;
typedef __attribute__((ext_vector_type(8))) short short8;
typedef __attribute__((ext_vector_type(4))) float f32x4;
#define MFMA_BF16(a, b, c) __builtin_amdgcn_mfma_f32_16x16x32_bf16(a, b, c, 0, 0, 0)

__device__ __forceinline__ float sigmoidf_(float x) { return 1.0f / (1.0f + expf(-x)); }

__device__ __forceinline__ u16t f2bf(float f) {
  u32t u = __float_as_uint(f);
  u = u + 0x7FFFu + ((u >> 16) & 1u);
  return (u16t)(u >> 16);
}
__device__ __forceinline__ u32t pk2(u16t a, u16t b) { return (u32t)a | ((u32t)b << 16); }

// ---------------- block reduction helper (blockDim == 256) ----------------
template<int N>
__device__ __forceinline__ void block_reduce_sum(float* v, float* scratch) {
  int lane = threadIdx.x & 63, wid = threadIdx.x >> 6;
#pragma unroll
  for (int i = 0; i < N; i++) {
    float x = v[i];
#pragma unroll
    for (int off = 1; off < 64; off <<= 1) x += __shfl_xor(x, off);
    if (lane == 0) scratch[wid * N + i] = x;
  }
  __syncthreads();
#pragma unroll
  for (int i = 0; i < N; i++)
    v[i] = scratch[i] + scratch[N + i] + scratch[2 * N + i] + scratch[3 * N + i];
  __syncthreads();
}

// ---------------- cast fp32 -> bf16 with column embed ----------------
__global__ __launch_bounds__(256) void castbf_kernel(
    const float* __restrict__ in, u16t* __restrict__ out,
    int n4, int lc2, int ldo, int ocol0, float scale) {
  int idx = blockIdx.x * 256 + threadIdx.x;
  if (idx >= n4) return;
  int e = idx * 4;
  int row = e >> lc2, col = e & ((1 << lc2) - 1);
  float4 v = *(const float4*)(in + (i64)e);
  uint2 o;
  o.x = pk2(f2bf(v.x * scale), f2bf(v.y * scale));
  o.y = pk2(f2bf(v.z * scale), f2bf(v.w * scale));
  *(uint2*)(out + (i64)row * ldo + ocol0 + col) = o;
}

// ---------------- transpose + cast: in fp32 [K][N] -> out bf16 [N][K] ----------------
__global__ __launch_bounds__(256) void transcast_kernel(
    const float* __restrict__ in, int ldin, int col0,
    u16t* __restrict__ out, int ldout) {
  __shared__ float tile[32][33];
  int tx = threadIdx.x & 31, ty = threadIdx.x >> 5;
  int nb = blockIdx.x * 32, kb = blockIdx.y * 32;
#pragma unroll
  for (int r = 0; r < 4; r++)
    tile[ty + r * 8][tx] = in[(i64)(kb + ty + r * 8) * ldin + col0 + nb + tx];
  __syncthreads();
#pragma unroll
  for (int r = 0; r < 4; r++)
    out[(i64)(nb + ty + r * 8) * ldout + kb + tx] = f2bf(tile[tx][ty + r * 8]);
}

// ---------------- bf16 MFMA GEMM: A[M][K] bf16, B[N][K] bf16, C[M][N] fp32 ----------------
__global__ __launch_bounds__(256) void gemm_bt_kernel(
    const u16t* __restrict__ A, const u16t* __restrict__ B,
    float* __restrict__ C, int K, int ldc) {
  __shared__ u16t As[128 * 40];
  __shared__ u16t Bs[128 * 40];
  int t = threadIdx.x;
  int n0 = blockIdx.x * 128, m0 = blockIdx.y * 128;
  int w = t >> 6, lane = t & 63;
  int l15 = lane & 15, quad = lane >> 4;
  int wm = (w & 1) * 64, wn = (w >> 1) * 64;
  f32x4 acc[4][4] = {};
  int srow = t >> 1, shalf = (t & 1) * 16;
  const u16t* Ag = A + (i64)(m0 + srow) * K + shalf;
  const u16t* Bg = B + (i64)(n0 + srow) * K + shalf;
  for (int k0 = 0; k0 < K; k0 += 32) {
    *(uint4*)&As[srow * 40 + shalf] = *(const uint4*)(Ag + k0);
    *(uint4*)&As[srow * 40 + shalf + 8] = *(const uint4*)(Ag + k0 + 8);
    *(uint4*)&Bs[srow * 40 + shalf] = *(const uint4*)(Bg + k0);
    *(uint4*)&Bs[srow * 40 + shalf + 8] = *(const uint4*)(Bg + k0 + 8);
    __syncthreads();
    short8 a[4], b[4];
#pragma unroll
    for (int mt = 0; mt < 4; mt++)
      a[mt] = *(const short8*)&As[(wm + mt * 16 + l15) * 40 + quad * 8];
#pragma unroll
    for (int nt = 0; nt < 4; nt++)
      b[nt] = *(const short8*)&Bs[(wn + nt * 16 + l15) * 40 + quad * 8];
#pragma unroll
    for (int mt = 0; mt < 4; mt++)
#pragma unroll
      for (int nt = 0; nt < 4; nt++)
        acc[mt][nt] = MFMA_BF16(a[mt], b[nt], acc[mt][nt]);
    __syncthreads();
  }
#pragma unroll
  for (int mt = 0; mt < 4; mt++) {
    int r0 = m0 + wm + mt * 16 + quad * 4;
#pragma unroll
    for (int nt = 0; nt < 4; nt++) {
      int cc = n0 + wn + nt * 16 + l15;
#pragma unroll
      for (int rg = 0; rg < 4; rg++)
        C[(i64)(r0 + rg) * ldc + cc] = acc[mt][nt][rg];
    }
  }
}

// ---------------- causal depthwise conv (K=4) + silu ----------------
__global__ __launch_bounds__(256) void conv_silu_kernel(
    const float* __restrict__ pre, int ldpre, int coff,
    const float* __restrict__ w, float* __restrict__ out) {
  int idx = blockIdx.x * 256 + threadIdx.x;
  int c = idx & (HIDD - 1);
  int row = idx >> 10;
  int l = row & (LL - 1);
  float4 wv = *(const float4*)(w + c * 4);
  const float* base = pre + (i64)row * ldpre + coff + c;
  float acc = wv.w * base[0];
  if (l >= 1) acc += wv.z * base[-ldpre];
  if (l >= 2) acc += wv.y * base[-2 * ldpre];
  if (l >= 3) acc += wv.x * base[-3 * ldpre];
  out[(i64)row * HIDD + c] = acc * sigmoidf_(acc);
}

// ---------------- beta = sigmoid(x @ Wb) ----------------
__global__ __launch_bounds__(256) void beta_kernel(
    const float* __restrict__ x, const float* __restrict__ Wb, float* __restrict__ beta) {
  int row = blockIdx.x, t = threadIdx.x;
  __shared__ float sc[16];
  float a[4] = {0, 0, 0, 0};
  for (int c = t; c < 1024; c += 256) {
    float xv = x[(i64)row * 1024 + c];
    float4 wv = *(const float4*)(Wb + c * 4);
    a[0] += xv * wv.x; a[1] += xv * wv.y; a[2] += xv * wv.z; a[3] += xv * wv.w;
  }
  block_reduce_sum<4>(a, sc);
  if (t == 0) {
#pragma unroll
    for (int g = 0; g < 4; g++) beta[row * 4 + g] = sigmoidf_(a[g]);
  }
}

// ---------------- l2norm(q,k), v*beta, kn*beta ----------------
__global__ __launch_bounds__(256) void preprocess_kernel(
    const float* __restrict__ q, const float* __restrict__ k, const float* __restrict__ v,
    const float* __restrict__ beta, float* __restrict__ qn, float* __restrict__ kn,
    float* __restrict__ vb, float* __restrict__ kb) {
  int row = blockIdx.x, t = threadIdx.x;
  __shared__ float sc[8];
  i64 base = (i64)row * 256 + t;
  float qv = q[base], kv = k[base], vv = v[base];
  float vals[2] = {qv * qv, kv * kv};
  block_reduce_sum<2>(vals, sc);
  float qi = rsqrtf(vals[0] + 1e-6f), ki = rsqrtf(vals[1] + 1e-6f);
  float bet = beta[row];
  float knv = kv * ki;
  qn[base] = qv * qi;
  kn[base] = knv;
  vb[base] = vv * bet;
  kb[base] = knv * bet;
}

// ---------------- phase A: per-chunk M, attn, UT-transform (u, w) — exact fp32 ----------------
__global__ __launch_bounds__(256) void phaseA_kernel(
    const float* __restrict__ qn, const float* __restrict__ kn,
    const float* __restrict__ vb, const float* __restrict__ kb,
    float* __restrict__ u_g, float* __restrict__ w_g, float* __restrict__ attn_g) {
  __shared__ float KN[32][260];
  __shared__ float Ms[32][32];
  int blk = blockIdx.x, t = threadIdx.x;
  int i = blk & 31, bh = blk >> 5;
  int rbase = ((bh >> 2) * LL + i * 32) * NH + (bh & 3);
  int bhn = bh * NCH + i;
#pragma unroll
  for (int ii = 0; ii < 8; ii++) {
    int fid = t + ii * 256;
    int c = fid >> 6, dq = (fid & 63) << 2;
    *(float4*)&KN[c][dq] = *(const float4*)(kn + (i64)(rbase + c * NH) * 256 + dq);
  }
  __syncthreads();
  int c = t >> 3, e0 = (t & 7) * 4;
  const float* kbp = kb + (i64)(rbase + c * NH) * 256;
  const float* qp = qn + (i64)(rbase + c * NH) * 256;
  float am[4] = {0, 0, 0, 0}, aa[4] = {0, 0, 0, 0};
  for (int d = 0; d < 256; d += 4) {
    float4 kv = *(const float4*)(kbp + d);
    float4 qv = *(const float4*)(qp + d);
#pragma unroll
    for (int z = 0; z < 4; z++) {
      float4 nv = *(const float4*)&KN[e0 + z][d];
      am[z] += kv.x * nv.x + kv.y * nv.y + kv.z * nv.z + kv.w * nv.w;
      aa[z] += qv.x * nv.x + qv.y * nv.y + qv.z * nv.z + qv.w * nv.w;
    }
  }
#pragma unroll
  for (int z = 0; z < 4; z++) {
    int e = e0 + z;
    Ms[c][e] = (e < c) ? am[z] : 0.0f;
    attn_g[(i64)bhn * 1024 + c * 32 + e] = (e <= c) ? aa[z] : 0.0f;
  }
  __syncthreads();
  float uc[32], wc[32];
#pragma unroll
  for (int cc = 0; cc < 32; cc++) {
    float uval = vb[(i64)(rbase + cc * NH) * 256 + t];
    float wval = kb[(i64)(rbase + cc * NH) * 256 + t];
#pragma unroll
    for (int c2 = 0; c2 < cc; c2++) {
      float m = Ms[cc][c2];
      uval -= m * uc[c2];
      wval -= m * wc[c2];
    }
    uc[cc] = uval; wc[cc] = wval;
    u_g[((i64)bhn * 32 + cc) * 256 + t] = uval;
    w_g[((i64)bhn * 32 + cc) * 256 + t] = wval;
  }
}

// ---------------- qn remap to delta layout [bh][l][d] bf16 ----------------
__global__ __launch_bounds__(256) void qnremap_kernel(
    const float* __restrict__ qn, u16t* __restrict__ out) {
  int row = blockIdx.x, t = threadIdx.x;
  int h = row & 3, bl = row >> 2;
  int b = bl >> 10, l = bl & 1023;
  i64 orow = ((i64)(b * 4 + h) * 1024 + l);
  out[orow * 256 + t] = f2bf(qn[(i64)row * 256 + t]);
}

// ---------------- kn chunk transpose: knT [bhn][d=256][c=32] bf16 ----------------
__global__ __launch_bounds__(256) void knT_kernel(
    const float* __restrict__ kn, u16t* __restrict__ out) {
  __shared__ float tile[32][260];
  int blk = blockIdx.x, t = threadIdx.x;
  int bh = blk >> 5, i = blk & 31;
  int b = bh >> 2, h = bh & 3;
  i64 rbase = ((i64)b * 1024 + i * 32) * 4 + h;
  int c = t >> 3, seg = (t & 7) * 32;
#pragma unroll
  for (int z = 0; z < 8; z++)
    *(float4*)&tile[c][seg + z * 4] = *(const float4*)(kn + (rbase + c * 4) * 256 + seg + z * 4);
  __syncthreads();
  int d = t;
  u16t o[32];
#pragma unroll
  for (int cc = 0; cc < 32; cc++) o[cc] = f2bf(tile[cc][d]);
#pragma unroll
  for (int z = 0; z < 4; z++) {
    uint4 vv;
    vv.x = pk2(o[z * 8 + 0], o[z * 8 + 1]);
    vv.y = pk2(o[z * 8 + 2], o[z * 8 + 3]);
    vv.z = pk2(o[z * 8 + 4], o[z * 8 + 5]);
    vv.w = pk2(o[z * 8 + 6], o[z * 8 + 7]);
    *(uint4*)(out + ((i64)blk * 256 + d) * 32 + z * 8) = vv;
  }
}

// ---------------- pass 1: sequential state scan (MFMA, S in fp32 acc) ----------------
__global__ __launch_bounds__(256) void pass1_kernel(
    const u16t* __restrict__ wbf, const u16t* __restrict__ knT,
    const float* __restrict__ u_g, u16t* __restrict__ Sst, u16t* __restrict__ upst) {
  __shared__ u16t Sbf[16 * 272];   // [j][d] bf16
  __shared__ u16t Ubf[16 * 40];    // [j][c] bf16
  int t = threadIdx.x, w = t >> 6, lane = t & 63;
  int l15 = lane & 15, quad = lane >> 4;
  int bh = blockIdx.x >> 4, jb = blockIdx.x & 15, j0 = jb * 16;
  for (int idx = t; idx < 16 * 272; idx += 256) Sbf[idx] = 0;
  f32x4 acc[4] = {};   // S[d = w*64 + dt*16 + quad*4 + reg][j0 + l15]
  __syncthreads();
  for (int i = 0; i < 32; i++) {
    i64 bhn = (i64)bh * 32 + i;
    if (w < 2) {
      // u' = u + (-w) @ S   (wbf pre-negated)
      int crow = w * 16 + l15;
      const u16t* ap = wbf + (bhn * 32 + crow) * 256 + quad * 8;
      f32x4 uacc;
      int cm = w * 16 + quad * 4;
#pragma unroll
      for (int r = 0; r < 4; r++)
        uacc[r] = u_g[(bhn * 32 + cm + r) * 256 + j0 + l15];
#pragma unroll
      for (int kd = 0; kd < 8; kd++) {
        short8 af = *(const short8*)(ap + kd * 32);
        short8 bf = *(const short8*)&Sbf[l15 * 272 + kd * 32 + quad * 8];
        uacc = MFMA_BF16(af, bf, uacc);
      }
      uint2 o;
      o.x = pk2(f2bf(uacc[0]), f2bf(uacc[1]));
      o.y = pk2(f2bf(uacc[2]), f2bf(uacc[3]));
      *(uint2*)&Ubf[l15 * 40 + cm] = o;
      *(uint2*)(upst + (bhn * 256 + j0 + l15) * 32 + cm) = o;
    } else {
      // copy S_i slice to global (pre-update)
      int lam = (w - 2) * 64 + lane;
      int jr = lam >> 3, seg = lam & 7;
#pragma unroll
      for (int z = 0; z < 4; z++) {
        uint4 vv = *(const uint4*)&Sbf[jr * 272 + seg * 32 + z * 8];
        *(uint4*)(Sst + (bhn * 256 + j0 + jr) * 256 + seg * 32 + z * 8) = vv;
      }
    }
    __syncthreads();
    // S += knT @ u'
    short8 bu = *(const short8*)&Ubf[l15 * 40 + quad * 8];
    int dbase = w * 64;
#pragma unroll
    for (int dt = 0; dt < 4; dt++) {
      short8 af = *(const short8*)(knT + (bhn * 256 + dbase + dt * 16 + l15) * 32 + quad * 8);
      acc[dt] = MFMA_BF16(af, bu, acc[dt]);
    }
#pragma unroll
    for (int dt = 0; dt < 4; dt++) {
      uint2 o;
      o.x = pk2(f2bf(acc[dt][0]), f2bf(acc[dt][1]));
      o.y = pk2(f2bf(acc[dt][2]), f2bf(acc[dt][3]));
      *(uint2*)&Sbf[l15 * 272 + dbase + dt * 16 + quad * 4] = o;
    }
    __syncthreads();
  }
}

// ---------------- pass 2: fully parallel per-chunk output (MFMA) ----------------
__global__ __launch_bounds__(256) void pass2_kernel(
    const u16t* __restrict__ qnbf, const u16t* __restrict__ Sst,
    const u16t* __restrict__ attnbf, const u16t* __restrict__ upst,
    float* __restrict__ dlt) {
  int t = threadIdx.x, w = t >> 6, lane = t & 63;
  int l15 = lane & 15, quad = lane >> 4;
  int bh = blockIdx.x >> 5, i = blockIdx.x & 31;
  i64 bhn = (i64)bh * 32 + i;
  int b_ = bh >> 2, h_ = bh & 3;
  f32x4 acc[2][4] = {};
  const u16t* qp0 = qnbf + ((i64)bh * 1024 + i * 32 + l15) * 256 + quad * 8;
  const u16t* qp1 = qp0 + 16 * 256;
  const u16t* sp = Sst + (bhn * 256 + w * 64 + l15) * 256 + quad * 8;
#pragma unroll
  for (int kd = 0; kd < 8; kd++) {
    short8 a0 = *(const short8*)(qp0 + kd * 32);
    short8 a1 = *(const short8*)(qp1 + kd * 32);
#pragma unroll
    for (int nt = 0; nt < 4; nt++) {
      short8 bf = *(const short8*)(sp + (i64)nt * 16 * 256 + kd * 32);
      acc[0][nt] = MFMA_BF16(a0, bf, acc[0][nt]);
      acc[1][nt] = MFMA_BF16(a1, bf, acc[1][nt]);
    }
  }
  short8 at0 = *(const short8*)(attnbf + bhn * 1024 + l15 * 32 + quad * 8);
  short8 at1 = *(const short8*)(attnbf + bhn * 1024 + (16 + l15) * 32 + quad * 8);
#pragma unroll
  for (int nt = 0; nt < 4; nt++) {
    short8 bu = *(const short8*)(upst + (bhn * 256 + w * 64 + nt * 16 + l15) * 32 + quad * 8);
    acc[0][nt] = MFMA_BF16(at0, bu, acc[0][nt]);
    acc[1][nt] = MFMA_BF16(at1, bu, acc[1][nt]);
  }
#pragma unroll
  for (int mt = 0; mt < 2; mt++) {
    int cbase = mt * 16 + quad * 4;
#pragma unroll
    for (int nt = 0; nt < 4; nt++) {
      int j = w * 64 + nt * 16 + l15;
#pragma unroll
      for (int rg = 0; rg < 4; rg++) {
        int l = i * 32 + cbase + rg;
        dlt[(((i64)b_ * 1024 + l) * 4 + h_) * 256 + j] = acc[mt][nt][rg];
      }
    }
  }
}

// ---------------- per-head depthwise causal FIR ----------------
__global__ __launch_bounds__(256) void fir_kernel(
    const float* __restrict__ v, const float* __restrict__ f, float* __restrict__ out, int K) {
  __shared__ float fb[256 * 31];
  int row = blockIdx.x, t = threadIdx.x;
  int h = row & 3, l = (row >> 2) & (LL - 1);
  for (int idx = t; idx < 256 * K; idx += 256) fb[idx] = f[h * 256 * K + idx];
  __syncthreads();
  float acc = 0.0f;
  int jmin = (K - 1) - l; if (jmin < 0) jmin = 0;
  for (int jj = jmin; jj < K; jj++) {
    int dl = jj - (K - 1);
    acc += fb[t * K + jj] * v[(i64)(row + dl * NH) * 256 + t];
  }
  out[(i64)row * 256 + t] = acc;
}

// ---------------- per-(row,branch) stats ----------------
__global__ __launch_bounds__(256) void stats_kernel(
    const float* __restrict__ fs, const float* __restrict__ fl,
    const float* __restrict__ dlt, const float* __restrict__ v, float* __restrict__ stat) {
  int row = blockIdx.x, t = threadIdx.x;
  __shared__ float sc[8];
  __shared__ float scm[4];
  const float* brs[4] = {fs, fl, dlt, v};
#pragma unroll
  for (int p = 0; p < 4; p++) {
    float x = brs[p][(i64)row * 256 + t];
    float vals[2] = {x, x * x};
    block_reduce_sum<2>(vals, sc);
    float m = x;
#pragma unroll
    for (int off = 1; off < 64; off <<= 1) m = fmaxf(m, __shfl_xor(m, off));
    int lane = t & 63, wid = t >> 6;
    if (lane == 0) scm[wid] = m;
    __syncthreads();
    if (t == 0) {
      float mx = fmaxf(fmaxf(scm[0], scm[1]), fmaxf(scm[2], scm[3]));
      stat[row * 12 + p * 3 + 0] = vals[0] * (1.0f / 256.0f);
      stat[row * 12 + p * 3 + 1] = sqrtf(fmaxf(vals[1] * (1.0f / 256.0f), 1e-8f));
      stat[row * 12 + p * 3 + 2] = mx;
    }
    __syncthreads();
  }
}

// ---------------- W1 stat-block column sums ----------------
__global__ __launch_bounds__(256) void wsum_kernel(const float* __restrict__ W1, float* __restrict__ Wsum) {
  int s = blockIdx.x, t = threadIdx.x;
  for (int o = t; o < 512; o += 256) {
    float acc = 0.0f;
    const float* p = W1 + (i64)(1024 + s * 256) * 512 + o;
    for (int r = 0; r < 256; r++) acc += p[r * 512];
    Wsum[s * 512 + o] = acc;
  }
}

// ---------------- gate MLP tail ----------------
__global__ __launch_bounds__(256) void gate_kernel(
    const float* __restrict__ hbase, const float* __restrict__ brW,
    const float* __restrict__ stat, const float* __restrict__ wsum,
    const float* __restrict__ gb1, const float* __restrict__ gW2,
    const float* __restrict__ gb2, const float* __restrict__ temp,
    const float* __restrict__ epsf, float* __restrict__ gw) {
  int row = blockIdx.x, t = threadIdx.x;
  int bl = row >> 2, h = row & 3;
  __shared__ float sc[16];
  float st[12];
#pragma unroll
  for (int s = 0; s < 12; s++) st[s] = stat[row * 12 + s];
  float lg[4] = {0, 0, 0, 0};
  for (int o = t; o < 512; o += 256) {
    float hm = hbase[(i64)bl * 512 + o] + brW[(i64)row * 512 + o] + gb1[o];
#pragma unroll
    for (int s = 0; s < 12; s++) hm += st[s] * wsum[s * 512 + o];
    float ge = 0.5f * hm * (1.0f + erff(hm * 0.70710678118654752f));
    float4 w2 = *(const float4*)(gW2 + o * 4);
    lg[0] += ge * w2.x; lg[1] += ge * w2.y; lg[2] += ge * w2.z; lg[3] += ge * w2.w;
  }
  block_reduce_sum<4>(lg, sc);
  if (t == 0) {
    float tt = fminf(fmaxf(temp[h], 0.2f), 10.0f);
    float l0 = (lg[0] + gb2[0]) / tt;
    float l1 = (lg[1] + gb2[1]) / tt;
    float l2 = (lg[2] + gb2[2]) / tt;
    float l3 = (lg[3] + gb2[3]) / tt;
    float m = fmaxf(fmaxf(l0, l1), fmaxf(l2, l3));
    float e0 = expf(l0 - m), e1 = expf(l1 - m), e2 = expf(l2 - m), e3 = expf(l3 - m);
    float ssum = e0 + e1 + e2 + e3;
    float w0 = e0 / ssum, w1 = e1 / ssum, w2 = e2 / ssum, w3 = e3 / ssum;
    w0 = fmaxf(w0, fminf(fmaxf(epsf[h * 4 + 0], 1e-7f), 0.1f));
    w1 = fmaxf(w1, fminf(fmaxf(epsf[h * 4 + 1], 1e-7f), 0.1f));
    w2 = fmaxf(w2, fminf(fmaxf(epsf[h * 4 + 2], 1e-7f), 0.1f));
    w3 = fmaxf(w3, fminf(fmaxf(epsf[h * 4 + 3], 1e-7f), 0.1f));
    float s2 = w0 + w1 + w2 + w3;
    gw[row * 4 + 0] = w0 / s2;
    gw[row * 4 + 1] = w1 / s2;
    gw[row * 4 + 2] = w2 / s2;
    gw[row * 4 + 3] = w3 / s2;
  }
}

// ---------------- weighted mix + RMS norm ----------------
__global__ __launch_bounds__(256) void mix_kernel(
    const float* __restrict__ fs, const float* __restrict__ fl,
    const float* __restrict__ dlt, const float* __restrict__ v,
    const float* __restrict__ gw, const float* __restrict__ onw, float* __restrict__ out) {
  int row = blockIdx.x, t = threadIdx.x;
  __shared__ float sc[4];
  i64 base = (i64)row * 256 + t;
  float4 wv = *(const float4*)(gw + row * 4);
  float o = wv.x * fs[base] + wv.y * fl[base] + wv.z * dlt[base] + wv.w * v[base];
  float vals[1] = {o * o};
  block_reduce_sum<1>(vals, sc);
  float scale = rsqrtf(vals[0] * (1.0f / 256.0f) + 1e-5f);
  out[base] = o * scale * onw[t];
}

extern "C" void kernel_launch(void* const* d_in, const int* in_sizes, int n_in,
                              void* d_out, int out_size, void* d_ws, size_t ws_size,
                              hipStream_t stream) {
  (void)in_sizes; (void)n_in; (void)out_size; (void)ws_size;
  const float* x    = (const float*)d_in[0];
  const float* Wq   = (const float*)d_in[1];
  const float* Wk   = (const float*)d_in[2];
  const float* Wv   = (const float*)d_in[3];
  const float* Wb   = (const float*)d_in[4];
  const float* qcw  = (const float*)d_in[5];
  const float* kcw  = (const float*)d_in[6];
  const float* vcw  = (const float*)d_in[7];
  const float* gW1  = (const float*)d_in[8];
  const float* gb1  = (const float*)d_in[9];
  const float* gW2  = (const float*)d_in[10];
  const float* gb2  = (const float*)d_in[11];
  const float* temp = (const float*)d_in[12];
  const float* epsf = (const float*)d_in[13];
  const float* onw  = (const float*)d_in[14];
  const float* Wo   = (const float*)d_in[15];
  const float* firs = (const float*)d_in[16];
  const float* firl = (const float*)d_in[17];
  float* out = (float*)d_out;

  float* ws = (float*)d_ws;
  // ---- workspace map (float offsets); regions reused once producer is dead ----
  // Liveness timeline for region [0 .. 8388608):
  //   qkv_pre (steps 2-3) -> attn_g @+4194304 (steps 5-6) -> S_store (step 7)
  //   -> brcat @+0 (step 10) / branchW @+4194304 (steps 10-11)
  float* qkv_pre  = ws + 0;                       // 2048*3072 fp32
  u16t*  S_store  = (u16t*)(ws + 0);              // 8*32*256*256 bf16
  u16t*  brcat    = (u16t*)(ws + 0);              // 8192*1024 bf16
  float* attn_g   = ws + 4194304;                 // 8*32*1024 fp32 (step5 write, step6 read)
  float* branchW  = ws + 4194304;                 // 8192*512 fp32 (step 10+)
  float* qbuf     = ws + 8388608;  float* qn = qbuf;   // l2norm in place
  float* kbuf     = ws + 10485760; float* kn = kbuf;
  float* vbuf     = ws + 12582912;
  float* vb       = ws + 14680064;                // dead after phaseA
  u16t*  w_bf     = (u16t*)(ws + 14680064);       // negated w, bf16 (after phaseA)
  u16t*  qn_bf    = (u16t*)(ws + 15728640);
  float* kb       = ws + 16777216;                // dead after phaseA
  float* hbase    = ws + 16777216;                // 2048*512 (step 10+)
  u16t*  attn_bf  = (u16t*)(ws + 17825792);       // step6 write, step7 read
  float* u_g      = ws + 18874368;                // dead after pass1
  u16t*  W1hT     = (u16t*)(ws + 18874368);       // step 10+
  u16t*  W1bT     = (u16t*)(ws + 19136512);
  u16t*  WoT      = (u16t*)(ws + 19398656);
  u16t*  omix_bf  = (u16t*)(ws + 19922944);
  float* w_g      = ws + 20971520;                // dead after castbf step 6
  float* omix     = ws + 20971520;                // step 11+
  u16t*  upst     = (u16t*)(ws + 23068672);
  u16t*  knT      = (u16t*)(ws + 24117248);
  float* dlt      = ws + 25165824;
  float* fs       = ws + 27262976;
  float* fl       = ws + 29360128;
  u16t*  xbf      = (u16t*)(ws + 31457280);
  u16t*  WqkvT    = (u16t*)(ws + 32505856);
  float* betab    = ws + 34078720;
  float* stat     = ws + 34086912;
  float* wsum     = ws + 34185216;
  float* gw       = ws + 34191360;

  // 1) casts + QKV weight transposes
  castbf_kernel<<<2048, 256, 0, stream>>>(x, xbf, 524288, 10, 1024, 0, 1.0f);
  transcast_kernel<<<dim3(32, 32), 256, 0, stream>>>(Wq, 1024, 0, WqkvT, 1024);
  transcast_kernel<<<dim3(32, 32), 256, 0, stream>>>(Wk, 1024, 0, WqkvT + 1024 * 1024, 1024);
  transcast_kernel<<<dim3(32, 32), 256, 0, stream>>>(Wv, 1024, 0, WqkvT + 2048 * 1024, 1024);
  // 2) QKV GEMM (bf16 MFMA)
  gemm_bt_kernel<<<dim3(24, 16), 256, 0, stream>>>(xbf, WqkvT, qkv_pre, 1024, 3072);
  // 3) conv + silu
  conv_silu_kernel<<<8192, 256, 0, stream>>>(qkv_pre, 3072, 0, qcw, qbuf);
  conv_silu_kernel<<<8192, 256, 0, stream>>>(qkv_pre, 3072, 1024, kcw, kbuf);
  conv_silu_kernel<<<8192, 256, 0, stream>>>(qkv_pre, 3072, 2048, vcw, vbuf);
  // 4) beta + preprocess
  beta_kernel<<<2048, 256, 0, stream>>>(x, Wb, betab);
  preprocess_kernel<<<8192, 256, 0, stream>>>(qbuf, kbuf, vbuf, betab, qn, kn, vb, kb);
  // 5) phase A (exact fp32)
  phaseA_kernel<<<256, 256, 0, stream>>>(qn, kn, vb, kb, u_g, w_g, attn_g);
  // 6) delta operand preps (bf16)
  castbf_kernel<<<2048, 256, 0, stream>>>(w_g, w_bf, 524288, 8, 256, 0, -1.0f);
  qnremap_kernel<<<8192, 256, 0, stream>>>(qn, qn_bf);
  knT_kernel<<<256, 256, 0, stream>>>(kn, knT);
  castbf_kernel<<<256, 256, 0, stream>>>(attn_g, attn_bf, 65536, 10, 1024, 0, 1.0f);
  // 7) delta-rule scan + parallel output
  pass1_kernel<<<128, 256, 0, stream>>>(w_bf, knT, u_g, S_store, upst);
  pass2_kernel<<<256, 256, 0, stream>>>(qn_bf, S_store, attn_bf, upst, dlt);
  // 8) FIR branches
  fir_kernel<<<8192, 256, 0, stream>>>(vbuf, firs, fs, 3);
  fir_kernel<<<8192, 256, 0, stream>>>(vbuf, firl, fl, 31);
  // 9) stats + wsum
  stats_kernel<<<8192, 256, 0, stream>>>(fs, fl, dlt, vbuf, stat);
  wsum_kernel<<<12, 256, 0, stream>>>(gW1, wsum);
  // 10) gate GEMMs (bf16 MFMA)
  transcast_kernel<<<dim3(16, 32), 256, 0, stream>>>(gW1, 512, 0, W1hT, 1024);
  transcast_kernel<<<dim3(16, 32), 256, 0, stream>>>(gW1 + (i64)4096 * 512, 512, 0, W1bT, 1024);
  gemm_bt_kernel<<<dim3(4, 16), 256, 0, stream>>>(xbf, W1hT, hbase, 1024, 512);
  castbf_kernel<<<2048, 256, 0, stream>>>(fs, brcat, 524288, 8, 1024, 0, 1.0f);
  castbf_kernel<<<2048, 256, 0, stream>>>(fl, brcat, 524288, 8, 1024, 256, 1.0f);
  castbf_kernel<<<2048, 256, 0, stream>>>(dlt, brcat, 524288, 8, 1024, 512, 1.0f);
  castbf_kernel<<<2048, 256, 0, stream>>>(vbuf, brcat, 524288, 8, 1024, 768, 1.0f);
  gemm_bt_kernel<<<dim3(4, 64), 256, 0, stream>>>(brcat, W1bT, branchW, 1024, 512);
  // 11) gate tail + mix
  gate_kernel<<<8192, 256, 0, stream>>>(hbase, branchW, stat, wsum, gb1, gW2, gb2, temp, epsf, gw);
  mix_kernel<<<8192, 256, 0, stream>>>(fs, fl, dlt, vbuf, gw, onw, omix);
  // 12) final projection (bf16 MFMA)
  castbf_kernel<<<2048, 256, 0, stream>>>(omix, omix_bf, 524288, 10, 1024, 0, 1.0f);
  transcast_kernel<<<dim3(32, 32), 256, 0, stream>>>(Wo, 1024, 0, WoT, 1024);
  gemm_bt_kernel<<<dim3(8, 16), 256, 0, stream>>>(omix_bf, WoT, out, 1024, 1024);
}